// Round 5
// baseline (193.074 us; speedup 1.0000x reference)
//
#include <hip/hip_runtime.h>
#include <hip/hip_cooperative_groups.h>
#include <math.h>

namespace cg = cooperative_groups;

#define B 16
#define N 1024
#define D 512
#define K 32
#define EPSF 1e-12f

// ws float offsets
#define WS_WT_F   0        // WT bf16 [32][512] = 16384 u16 = 8192 f
#define WS_CT_F   8192     // CT f32 [32][512] = 16384 f
#define WS_ASP_F  24576    // assign partials [1024][32] f32
#define WS_ENTP_F 57344    // [1024]
#define WS_MSKP_F 58368    // [1024]
#define WS_PART_F 59392    // parts bf16 [32][16][32][512] = 8388608 u16

#define OFF_DIST 262144
#define OFF_ENT  262656

typedef __attribute__((ext_vector_type(8))) short s16x8;
typedef __attribute__((ext_vector_type(4))) short s16x4;
typedef __attribute__((ext_vector_type(4))) float f32x4;

__device__ __forceinline__ ushort f2b(float f) {
    unsigned u = __builtin_bit_cast(unsigned, f);
    u += 0x7fffu + ((u >> 16) & 1u);   // RTNE
    return (ushort)(u >> 16);
}
__device__ __forceinline__ float b2f(ushort u) {
    return __builtin_bit_cast(float, (unsigned)u << 16);
}

struct SharedA {
    ushort xs[4 * 2048];     // 16KB per-wave QK x tiles (swizzled)
    ushort xsT[512 * 36];    // 36KB x^T [d][n+pad]; reused as stg
    ushort tls[32 * 32];     // 2KB t^T [k][n]
    float4 accsh[2 * 128];   // 4KB
    float ssqsh[32], invsh[32];
    float pm[256];           // phase B
    float asL[32];
    float red[4];
};

// ---- prologue helpers ----
__device__ __forceinline__ void prep8(int bid, int t, const float* __restrict__ Wf,
    const float* __restrict__ cent, float* __restrict__ ws)
{
    if (bid < 4) {
        int kk = bid * 8 + (t >> 5);
        int dseg = (t & 31) * 16;
        ushort* wt = (ushort*)(ws + WS_WT_F);
        s16x8 v0, v1;
        #pragma unroll
        for (int e = 0; e < 8; ++e) v0[e] = f2b(Wf[(dseg + e) * 32 + kk]);
        #pragma unroll
        for (int e = 0; e < 8; ++e) v1[e] = f2b(Wf[(dseg + 8 + e) * 32 + kk]);
        *(s16x8*)(wt + kk * 512 + dseg) = v0;
        *(s16x8*)(wt + kk * 512 + dseg + 8) = v1;
    } else if (bid < 8) {
        int kk = (bid - 4) * 8 + (t >> 5);
        int dseg = (t & 31) * 16;
        float* ct = ws + WS_CT_F;
        #pragma unroll
        for (int q = 0; q < 4; ++q) {
            float4 v;
            v.x = cent[(dseg + q * 4 + 0) * 32 + kk];
            v.y = cent[(dseg + q * 4 + 1) * 32 + kk];
            v.z = cent[(dseg + q * 4 + 2) * 32 + kk];
            v.w = cent[(dseg + q * 4 + 3) * 32 + kk];
            *(float4*)(ct + kk * 512 + dseg + q * 4) = v;
        }
    }
}

// ---- phase A: QK softmax + fused VLAD partials (R4-verified body) ----
__device__ __forceinline__ void phaseA(int bid, int tid,
    const float* __restrict__ x, const float* __restrict__ mask,
    const float* __restrict__ bias, float* __restrict__ ws,
    ushort* __restrict__ parts, SharedA& sh)
{
    const int b = bid >> 5;
    const int s = bid & 31;
    const int w = tid >> 6;
    const int rw = w & 1, dw = w >> 1;
    const int l = tid & 63;
    const int g = l >> 4, lo = l & 15;
    const int n0 = s * 32 + rw * 16;
    const int p = bid * 2 + rw;
    const ushort* wt = (const ushort*)(ws + WS_WT_F);

    ushort* xw = sh.xs + w * 2048;
    float ssq[8] = {0.f, 0.f, 0.f, 0.f, 0.f, 0.f, 0.f, 0.f};
    f32x4 acc[2] = {{0.f, 0.f, 0.f, 0.f}, {0.f, 0.f, 0.f, 0.f}};
    const float4* xg = (const float4*)(x + (size_t)(b * N + n0) * D);

    #pragma unroll
    for (int cc = 0; cc < 2; ++cc) {
        const int c = dw * 2 + cc;
        float4 fv[8];
        #pragma unroll
        for (int j = 0; j < 8; ++j) {
            int idx = l + 64 * j;
            fv[j] = xg[(idx >> 5) * 128 + c * 32 + (idx & 31)];
        }
        #pragma unroll
        for (int j = 0; j < 8; ++j)
            ssq[j] += fv[j].x * fv[j].x + fv[j].y * fv[j].y
                    + fv[j].z * fv[j].z + fv[j].w * fv[j].w;
        #pragma unroll
        for (int j = 0; j < 8; ++j) {
            int idx = l + 64 * j;
            int r = idx >> 5, c4 = idx & 31;
            unsigned bo = (unsigned)(c4 * 8) ^ (unsigned)((r & 7) << 4);
            s16x4 sv = { (short)f2b(fv[j].x), (short)f2b(fv[j].y),
                         (short)f2b(fv[j].z), (short)f2b(fv[j].w) };
            *(s16x4*)&xw[r * 128 + (bo >> 1)] = sv;
            int nn = rw * 16 + r;
            int dbase = c * 128 + c4 * 4;
            sh.xsT[(dbase + 0) * 36 + nn] = (ushort)sv[0];
            sh.xsT[(dbase + 1) * 36 + nn] = (ushort)sv[1];
            sh.xsT[(dbase + 2) * 36 + nn] = (ushort)sv[2];
            sh.xsT[(dbase + 3) * 36 + nn] = (ushort)sv[3];
        }
        #pragma unroll
        for (int ks = 0; ks < 4; ++ks) {
            unsigned bo = (unsigned)(ks * 64 + g * 16) ^ (unsigned)((lo & 7) << 4);
            s16x8 bfrag = *(const s16x8*)&xw[lo * 128 + (bo >> 1)];
            int dglob = c * 128 + ks * 32 + g * 8;
            s16x8 a0 = *(const s16x8*)(wt + (size_t)lo * 512 + dglob);
            s16x8 a1 = *(const s16x8*)(wt + (size_t)(16 + lo) * 512 + dglob);
            acc[0] = __builtin_amdgcn_mfma_f32_16x16x32_bf16(a0, bfrag, acc[0], 0, 0, 0);
            acc[1] = __builtin_amdgcn_mfma_f32_16x16x32_bf16(a1, bfrag, acc[1], 0, 0, 0);
        }
    }

    #pragma unroll
    for (int j = 0; j < 8; ++j) {
        #pragma unroll
        for (int m = 16; m; m >>= 1) ssq[j] += __shfl_xor(ssq[j], m);
    }
    if (dw == 1) {
        if ((l & 31) == 0) {
            #pragma unroll
            for (int j = 0; j < 8; ++j)
                sh.ssqsh[rw * 16 + (l >> 5) + 2 * j] = ssq[j];
        }
        sh.accsh[rw * 128 + l * 2 + 0] = *(float4*)&acc[0];
        sh.accsh[rw * 128 + l * 2 + 1] = *(float4*)&acc[1];
    }
    __syncthreads();
    if (dw == 0) {
        float4 o0 = sh.accsh[rw * 128 + l * 2 + 0];
        float4 o1 = sh.accsh[rw * 128 + l * 2 + 1];
        acc[0][0] += o0.x; acc[0][1] += o0.y; acc[0][2] += o0.z; acc[0][3] += o0.w;
        acc[1][0] += o1.x; acc[1][1] += o1.y; acc[1][2] += o1.z; acc[1][3] += o1.w;
        if ((l & 31) == 0) {
            #pragma unroll
            for (int j = 0; j < 8; ++j) {
                int r = (l >> 5) + 2 * j;
                sh.invsh[rw * 16 + r] = 1.f / fmaxf(sqrtf(ssq[j] + sh.ssqsh[rw * 16 + r]), EPSF);
            }
        }
    }
    __syncthreads();
    if (dw == 0) {
        const float inv = sh.invsh[rw * 16 + lo];
        const float mv = mask[b * N + n0 + lo];
        float lg[2][4];
        #pragma unroll
        for (int kt = 0; kt < 2; ++kt)
            #pragma unroll
            for (int r = 0; r < 4; ++r)
                lg[kt][r] = (acc[kt][r] * inv + bias[kt * 16 + g * 4 + r]) * mv;
        float mx = lg[0][0];
        #pragma unroll
        for (int kt = 0; kt < 2; ++kt)
            #pragma unroll
            for (int r = 0; r < 4; ++r) mx = fmaxf(mx, lg[kt][r]);
        mx = fmaxf(mx, __shfl_xor(mx, 16));
        mx = fmaxf(mx, __shfl_xor(mx, 32));
        float e[2][4], sum = 0.f;
        #pragma unroll
        for (int kt = 0; kt < 2; ++kt)
            #pragma unroll
            for (int r = 0; r < 4; ++r) { e[kt][r] = __expf(lg[kt][r] - mx); sum += e[kt][r]; }
        sum += __shfl_xor(sum, 16);
        sum += __shfl_xor(sum, 32);
        const float rs = mv / sum;
        float sa[2][4], ent = 0.f;
        #pragma unroll
        for (int kt = 0; kt < 2; ++kt)
            #pragma unroll
            for (int r = 0; r < 4; ++r) {
                sa[kt][r] = e[kt][r] * rs;
                ent += sa[kt][r] > 0.f ? -sa[kt][r] * __log2f(sa[kt][r]) : 0.f;
            }
        #pragma unroll
        for (int m = 32; m; m >>= 1) ent += __shfl_xor(ent, m);
        if (l == 0) ws[WS_ENTP_F + p] = ent;
        float mp = mv;
        #pragma unroll
        for (int m = 8; m; m >>= 1) mp += __shfl_xor(mp, m);
        if (l == 0) ws[WS_MSKP_F + p] = mp;
        #pragma unroll
        for (int kt = 0; kt < 2; ++kt)
            #pragma unroll
            for (int r = 0; r < 4; ++r) {
                float av = sa[kt][r];
                #pragma unroll
                for (int m = 8; m; m >>= 1) av += __shfl_xor(av, m);
                if (lo == 0) ws[WS_ASP_F + p * 32 + kt * 16 + g * 4 + r] = av;
            }
        #pragma unroll
        for (int kt = 0; kt < 2; ++kt)
            #pragma unroll
            for (int r = 0; r < 4; ++r)
                sh.tls[(kt * 16 + g * 4 + r) * 32 + rw * 16 + lo] = f2b(sa[kt][r] * inv);
    }
    __syncthreads();   // tls ready

    // VLAD phase: wave w owns d-quarter [w*128, w*128+128)
    f32x4 acc2[2][8];
    #pragma unroll
    for (int kt = 0; kt < 2; ++kt)
        #pragma unroll
        for (int dt = 0; dt < 8; ++dt)
            acc2[kt][dt] = (f32x4){0.f, 0.f, 0.f, 0.f};
    {
        s16x8 av0 = *(const s16x8*)&sh.tls[lo * 32 + g * 8];
        s16x8 av1 = *(const s16x8*)&sh.tls[(16 + lo) * 32 + g * 8];
        #pragma unroll
        for (int dt = 0; dt < 8; ++dt) {
            int d = w * 128 + dt * 16 + lo;
            s16x4 b0 = *(const s16x4*)&sh.xsT[d * 36 + g * 8];
            s16x4 b1 = *(const s16x4*)&sh.xsT[d * 36 + g * 8 + 4];
            s16x8 bv;
            bv[0] = b0[0]; bv[1] = b0[1]; bv[2] = b0[2]; bv[3] = b0[3];
            bv[4] = b1[0]; bv[5] = b1[1]; bv[6] = b1[2]; bv[7] = b1[3];
            acc2[0][dt] = __builtin_amdgcn_mfma_f32_16x16x32_bf16(av0, bv, acc2[0][dt], 0, 0, 0);
            acc2[1][dt] = __builtin_amdgcn_mfma_f32_16x16x32_bf16(av1, bv, acc2[1][dt], 0, 0, 0);
        }
    }
    __syncthreads();   // xsT reads done; reuse as staging [32k][520]
    ushort* stg = sh.xsT;
    #pragma unroll
    for (int kt = 0; kt < 2; ++kt)
        #pragma unroll
        for (int dt = 0; dt < 8; ++dt)
            #pragma unroll
            for (int r = 0; r < 4; ++r)
                stg[(kt * 16 + g * 4 + r) * 520 + w * 128 + dt * 16 + lo] = f2b(acc2[kt][dt][r]);
    __syncthreads();
    #pragma unroll
    for (int j = 0; j < 8; ++j) {
        int k = w * 8 + j;
        s16x8 v = *(const s16x8*)&stg[k * 520 + l * 8];
        *(s16x8*)(parts + ((size_t)(s * 16 + b) * 32 + k) * 512 + l * 8) = v;
    }
}

// ---- phase B: reductions + vlad finalize (256 threads) ----
__device__ __forceinline__ void phaseB(int bid, int t, const float* __restrict__ ws,
    const ushort* __restrict__ parts, float* __restrict__ out, SharedA& sh)
{
    const int b = bid >> 5, k = bid & 31;
    {
        int kk = t & 31, i = t >> 5;   // 0..7
        float a = 0.f;
        #pragma unroll
        for (int ii = 0; ii < 8; ++ii)
            a += ws[WS_ASP_F + (size_t)(b * 64 + ii * 8 + i) * 32 + kk];
        sh.pm[t] = a;
    }
    __syncthreads();
    if (t < 32) {
        float a = 0.f;
        #pragma unroll
        for (int i = 0; i < 8; ++i) a += sh.pm[i * 32 + t];
        sh.asL[t] = a;
    }
    __syncthreads();
    if (k == 0 && t < 32) {
        float a = sh.asL[t];
        float mx = a;
        #pragma unroll
        for (int m = 16; m; m >>= 1) mx = fmaxf(mx, __shfl_xor(mx, m));
        float e = __expf(a - mx), ssum = e;
        #pragma unroll
        for (int m = 16; m; m >>= 1) ssum += __shfl_xor(ssum, m);
        out[OFF_DIST + b * 32 + t] = a - mx - logf(ssum);
    }
    if (bid == 0 && (t >> 6) == 1) {
        int l = t & 63;
        float es = 0.f, ms = 0.f;
        for (int i = l; i < 1024; i += 64) {
            es += ws[WS_ENTP_F + i];
            ms += ws[WS_MSKP_F + i];
        }
        #pragma unroll
        for (int m = 32; m; m >>= 1) { es += __shfl_xor(es, m); ms += __shfl_xor(ms, m); }
        if (l == 0) out[OFF_ENT] = es / ms;
    }
    const float as = sh.asL[k];
    const int d0 = t * 2;
    float a0 = 0.f, a1 = 0.f;
    for (int s = 0; s < 32; ++s) {
        unsigned v = *(const unsigned*)(parts + ((size_t)(s * 16 + b) * 32 + k) * 512 + d0);
        a0 += b2f((ushort)(v & 0xffffu));
        a1 += b2f((ushort)(v >> 16));
    }
    float2 ctv = *(const float2*)(ws + WS_CT_F + (size_t)k * 512 + d0);
    float v0 = a0 - ctv.x * as;
    float v1 = a1 - ctv.y * as;
    float sq = v0 * v0 + v1 * v1;
    #pragma unroll
    for (int m = 32; m; m >>= 1) sq += __shfl_xor(sq, m);
    if ((t & 63) == 0) sh.red[t >> 6] = sq;
    __syncthreads();
    float sc = 1.f / fmaxf(sqrtf(sh.red[0] + sh.red[1] + sh.red[2] + sh.red[3]), EPSF);
    float2 o = make_float2(v0 * sc, v1 * sc);
    *(float2*)(out + (size_t)(b * 32 + k) * 512 + d0) = o;
}

// ---- fused cooperative kernel ----
__global__ __launch_bounds__(256, 2) void kFused(const float* __restrict__ x,
    const float* __restrict__ mask, const float* __restrict__ Wf,
    const float* __restrict__ bias, const float* __restrict__ cent,
    float* __restrict__ ws, float* __restrict__ out)
{
    __shared__ SharedA sh;
    cg::grid_group grid = cg::this_grid();
    const int bid = blockIdx.x;
    const int t = threadIdx.x;
    ushort* parts = (ushort*)(ws + WS_PART_F);

    prep8(bid, t, Wf, cent, ws);
    grid.sync();
    phaseA(bid, t, x, mask, bias, ws, parts, sh);
    __threadfence();
    grid.sync();
    phaseB(bid, t, ws, parts, out, sh);
}

// ---- fallback path (3 launches, R4-equivalent) ----
__global__ __launch_bounds__(256) void k0_fb(const float* __restrict__ Wf,
    const float* __restrict__ cent, float* __restrict__ ws)
{
    prep8(blockIdx.x, threadIdx.x, Wf, cent, ws);
}
__global__ __launch_bounds__(256, 2) void kA_fb(const float* __restrict__ x,
    const float* __restrict__ mask, const float* __restrict__ bias,
    float* __restrict__ ws, ushort* __restrict__ parts)
{
    __shared__ SharedA sh;
    phaseA(blockIdx.x, threadIdx.x, x, mask, bias, ws, parts, sh);
}
__global__ __launch_bounds__(256, 2) void kC_fb(const float* __restrict__ ws,
    const ushort* __restrict__ parts, float* __restrict__ out)
{
    __shared__ SharedA sh;
    phaseB(blockIdx.x, threadIdx.x, ws, parts, out, sh);
}

extern "C" void kernel_launch(void* const* d_in, const int* in_sizes, int n_in,
                              void* d_out, int out_size, void* d_ws, size_t ws_size,
                              hipStream_t stream)
{
    const float* x    = (const float*)d_in[0];
    const float* mask = (const float*)d_in[1];
    const float* W    = (const float*)d_in[2];
    const float* bias = (const float*)d_in[3];
    const float* cent = (const float*)d_in[4];
    float* out = (float*)d_out;
    float* ws  = (float*)d_ws;
    ushort* parts = (ushort*)(ws + WS_PART_F);

    void* args[] = { (void*)&x, (void*)&mask, (void*)&W, (void*)&bias,
                     (void*)&cent, (void*)&ws, (void*)&out };
    hipError_t err = hipLaunchCooperativeKernel(
        reinterpret_cast<void*>(kFused), dim3(512), dim3(256), args, 0, stream);
    if (err != hipSuccess) {
        k0_fb<<<dim3(8), dim3(256), 0, stream>>>(W, cent, ws);
        kA_fb<<<dim3(512), dim3(256), 0, stream>>>(x, mask, bias, ws, parts);
        kC_fb<<<dim3(512), dim3(256), 0, stream>>>(ws, parts, out);
    }
}

// Round 6
// 30.154 us; speedup vs baseline: 6.4029x; 6.4029x over previous
//
#include <hip/hip_runtime.h>
#include <math.h>

#define B 16
#define N 1024
#define D 512
#define K 32
#define EPSF 1e-12f

// ws float offsets
#define WS_CT_F   0        // CT f32 [32][512] = 16384
#define WS_ASP_F  16384    // assign partials [1024][32]
#define WS_ENTP_F 49152    // [1024]
#define WS_MSKP_F 50176    // [1024]
#define WS_PART_F 51200    // parts bf16 [16][16][32][512] = 4194304 u16

#define OFF_DIST 262144
#define OFF_ENT  262656

typedef __attribute__((ext_vector_type(8))) short s16x8;
typedef __attribute__((ext_vector_type(4))) short s16x4;
typedef __attribute__((ext_vector_type(4))) float f32x4;

__device__ __forceinline__ ushort f2b(float f) {
    unsigned u = __builtin_bit_cast(unsigned, f);
    u += 0x7fffu + ((u >> 16) & 1u);   // RTNE
    return (ushort)(u >> 16);
}
__device__ __forceinline__ float b2f(ushort u) {
    return __builtin_bit_cast(float, (unsigned)u << 16);
}

struct SH {
    union U {
        ushort wtl[32 * 512];                    // 32KB W bf16 (prep only)
        struct Q {
            ushort xs[4 * 2048];                 // 16KB per-wave QK tiles
            ushort xsT[512 * 36];                // 36KB x^T / stg
        } q;
    } u;                                         // 52KB
    ushort tls[32 * 32];                         // 2KB t^T
    float4 accsh[2 * 128];                       // 4KB
    float ssqsh[32], invsh[32];
};

// kA2: 256 blocks (b, s64) x 256 thr; each handles 64 rows (2 tiles of 32).
// Prologue: CT slice + W->bf16 LDS + A-frag hoist to registers.
// Per tile: QK MFMA + fused masked softmax + VLAD MFMA (acc across tiles).
// Epilogue: bf16 parts via LDS staging, coalesced 16B stores.
__global__ __launch_bounds__(256, 2) void kA2(const float* __restrict__ x,
    const float* __restrict__ mask, const float* __restrict__ Wf,
    const float* __restrict__ bias, const float* __restrict__ cent,
    float* __restrict__ ws, ushort* __restrict__ parts)
{
    __shared__ SH sh;
    const int bid = blockIdx.x;          // b*16 + s64
    const int b = bid >> 4;
    const int s64 = bid & 15;
    const int tid = threadIdx.x;
    const int w = tid >> 6;
    const int rw = w & 1, dw = w >> 1;
    const int l = tid & 63;
    const int g = l >> 4, lo = l & 15;

    // CT slice: 2 d-rows per block
    if (tid < 64) {
        int k = tid & 31, dd = tid >> 5;
        int d = bid * 2 + dd;
        ws[WS_CT_F + k * 512 + d] = cent[d * 32 + k];
    }
    // W[d][k] f32 -> wtl[k][d] bf16 (swizzled), all threads (R3-verified)
    {
        const float4* Wg = (const float4*)Wf;
        #pragma unroll
        for (int i = 0; i < 16; ++i) {
            int f4 = tid + i * 256;
            float4 v = Wg[f4];
            int d = f4 >> 3, k4 = (f4 & 7) << 2;
            float vv[4] = {v.x, v.y, v.z, v.w};
            #pragma unroll
            for (int j = 0; j < 4; ++j) {
                int k = k4 + j;
                sh.u.wtl[(k * 512 + d) ^ ((k & 7) << 3)] = f2b(vv[j]);
            }
        }
    }
    __syncthreads();
    // hoist this wave's A-fragments into registers (wtl dead afterwards)
    s16x8 afr0[2][4], afr1[2][4];
    #pragma unroll
    for (int cc = 0; cc < 2; ++cc)
        #pragma unroll
        for (int ks = 0; ks < 4; ++ks) {
            int dglob = (dw * 2 + cc) * 128 + ks * 32 + g * 8;
            afr0[cc][ks] = *(const s16x8*)&sh.u.wtl[(lo * 512 + dglob) ^ ((lo & 7) << 3)];
            afr1[cc][ks] = *(const s16x8*)&sh.u.wtl[((16 + lo) * 512 + dglob) ^ ((lo & 7) << 3)];
        }
    __syncthreads();   // wtl region now reusable as xs/xsT

    ushort* xw = sh.u.q.xs + w * 2048;
    ushort* xsT = sh.u.q.xsT;

    f32x4 acc2[2][8];
    #pragma unroll
    for (int kt = 0; kt < 2; ++kt)
        #pragma unroll
        for (int dt = 0; dt < 8; ++dt)
            acc2[kt][dt] = (f32x4){0.f, 0.f, 0.f, 0.f};

    #pragma unroll
    for (int tile = 0; tile < 2; ++tile) {
        const int n0 = s64 * 64 + tile * 32 + rw * 16;
        const int p = bid * 4 + tile * 2 + rw;

        float ssq[8] = {0.f, 0.f, 0.f, 0.f, 0.f, 0.f, 0.f, 0.f};
        f32x4 acc[2] = {{0.f, 0.f, 0.f, 0.f}, {0.f, 0.f, 0.f, 0.f}};
        const float4* xg = (const float4*)(x + (size_t)(b * N + n0) * D);

        #pragma unroll
        for (int cc = 0; cc < 2; ++cc) {
            const int c = dw * 2 + cc;
            float4 fv[8];
            #pragma unroll
            for (int j = 0; j < 8; ++j) {
                int idx = l + 64 * j;
                fv[j] = xg[(idx >> 5) * 128 + c * 32 + (idx & 31)];
            }
            #pragma unroll
            for (int j = 0; j < 8; ++j)
                ssq[j] += fv[j].x * fv[j].x + fv[j].y * fv[j].y
                        + fv[j].z * fv[j].z + fv[j].w * fv[j].w;
            #pragma unroll
            for (int j = 0; j < 8; ++j) {
                int idx = l + 64 * j;
                int r = idx >> 5, c4 = idx & 31;
                unsigned bo = (unsigned)(c4 * 8) ^ (unsigned)((r & 7) << 4);
                s16x4 sv = { (short)f2b(fv[j].x), (short)f2b(fv[j].y),
                             (short)f2b(fv[j].z), (short)f2b(fv[j].w) };
                *(s16x4*)&xw[r * 128 + (bo >> 1)] = sv;
                int nn = rw * 16 + r;
                int dbase = c * 128 + c4 * 4;
                xsT[(dbase + 0) * 36 + nn] = (ushort)sv[0];
                xsT[(dbase + 1) * 36 + nn] = (ushort)sv[1];
                xsT[(dbase + 2) * 36 + nn] = (ushort)sv[2];
                xsT[(dbase + 3) * 36 + nn] = (ushort)sv[3];
            }
            #pragma unroll
            for (int ks = 0; ks < 4; ++ks) {
                unsigned bo = (unsigned)(ks * 64 + g * 16) ^ (unsigned)((lo & 7) << 4);
                s16x8 bfrag = *(const s16x8*)&xw[lo * 128 + (bo >> 1)];
                acc[0] = __builtin_amdgcn_mfma_f32_16x16x32_bf16(afr0[cc][ks], bfrag, acc[0], 0, 0, 0);
                acc[1] = __builtin_amdgcn_mfma_f32_16x16x32_bf16(afr1[cc][ks], bfrag, acc[1], 0, 0, 0);
            }
        }

        // per-row sumsq butterfly
        #pragma unroll
        for (int j = 0; j < 8; ++j) {
            #pragma unroll
            for (int m = 16; m; m >>= 1) ssq[j] += __shfl_xor(ssq[j], m);
        }
        if (dw == 1) {
            if ((l & 31) == 0) {
                #pragma unroll
                for (int j = 0; j < 8; ++j)
                    sh.ssqsh[rw * 16 + (l >> 5) + 2 * j] = ssq[j];
            }
            sh.accsh[rw * 128 + l * 2 + 0] = *(float4*)&acc[0];
            sh.accsh[rw * 128 + l * 2 + 1] = *(float4*)&acc[1];
        }
        __syncthreads();
        if (dw == 0) {
            float4 o0 = sh.accsh[rw * 128 + l * 2 + 0];
            float4 o1 = sh.accsh[rw * 128 + l * 2 + 1];
            acc[0][0] += o0.x; acc[0][1] += o0.y; acc[0][2] += o0.z; acc[0][3] += o0.w;
            acc[1][0] += o1.x; acc[1][1] += o1.y; acc[1][2] += o1.z; acc[1][3] += o1.w;
            if ((l & 31) == 0) {
                #pragma unroll
                for (int j = 0; j < 8; ++j) {
                    int r = (l >> 5) + 2 * j;
                    sh.invsh[rw * 16 + r] = 1.f / fmaxf(sqrtf(ssq[j] + sh.ssqsh[rw * 16 + r]), EPSF);
                }
            }
        }
        __syncthreads();
        if (dw == 0) {
            const float inv = sh.invsh[rw * 16 + lo];
            const float mv = mask[b * N + n0 + lo];
            float lg[2][4];
            #pragma unroll
            for (int kt = 0; kt < 2; ++kt)
                #pragma unroll
                for (int r = 0; r < 4; ++r)
                    lg[kt][r] = (acc[kt][r] * inv + bias[kt * 16 + g * 4 + r]) * mv;
            float mx = lg[0][0];
            #pragma unroll
            for (int kt = 0; kt < 2; ++kt)
                #pragma unroll
                for (int r = 0; r < 4; ++r) mx = fmaxf(mx, lg[kt][r]);
            mx = fmaxf(mx, __shfl_xor(mx, 16));
            mx = fmaxf(mx, __shfl_xor(mx, 32));
            float e[2][4], sum = 0.f;
            #pragma unroll
            for (int kt = 0; kt < 2; ++kt)
                #pragma unroll
                for (int r = 0; r < 4; ++r) { e[kt][r] = __expf(lg[kt][r] - mx); sum += e[kt][r]; }
            sum += __shfl_xor(sum, 16);
            sum += __shfl_xor(sum, 32);
            const float rs = mv / sum;
            float sa[2][4], ent = 0.f;
            #pragma unroll
            for (int kt = 0; kt < 2; ++kt)
                #pragma unroll
                for (int r = 0; r < 4; ++r) {
                    sa[kt][r] = e[kt][r] * rs;
                    ent += sa[kt][r] > 0.f ? -sa[kt][r] * __log2f(sa[kt][r]) : 0.f;
                }
            #pragma unroll
            for (int m = 32; m; m >>= 1) ent += __shfl_xor(ent, m);
            if (l == 0) ws[WS_ENTP_F + p] = ent;
            float mp = mv;
            #pragma unroll
            for (int m = 8; m; m >>= 1) mp += __shfl_xor(mp, m);
            if (l == 0) ws[WS_MSKP_F + p] = mp;
            #pragma unroll
            for (int kt = 0; kt < 2; ++kt)
                #pragma unroll
                for (int r = 0; r < 4; ++r) {
                    float av = sa[kt][r];
                    #pragma unroll
                    for (int m = 8; m; m >>= 1) av += __shfl_xor(av, m);
                    if (lo == 0) ws[WS_ASP_F + p * 32 + kt * 16 + g * 4 + r] = av;
                }
            #pragma unroll
            for (int kt = 0; kt < 2; ++kt)
                #pragma unroll
                for (int r = 0; r < 4; ++r)
                    sh.tls[(kt * 16 + g * 4 + r) * 32 + rw * 16 + lo] = f2b(sa[kt][r] * inv);
        }
        __syncthreads();   // tls ready

        // VLAD: wave w owns d-quarter [w*128, w*128+128); accumulate over tiles
        {
            s16x8 av0 = *(const s16x8*)&sh.tls[lo * 32 + g * 8];
            s16x8 av1 = *(const s16x8*)&sh.tls[(16 + lo) * 32 + g * 8];
            #pragma unroll
            for (int dt = 0; dt < 8; ++dt) {
                int d = w * 128 + dt * 16 + lo;
                s16x4 b0 = *(const s16x4*)&xsT[d * 36 + g * 8];
                s16x4 b1 = *(const s16x4*)&xsT[d * 36 + g * 8 + 4];
                s16x8 bv;
                bv[0] = b0[0]; bv[1] = b0[1]; bv[2] = b0[2]; bv[3] = b0[3];
                bv[4] = b1[0]; bv[5] = b1[1]; bv[6] = b1[2]; bv[7] = b1[3];
                acc2[0][dt] = __builtin_amdgcn_mfma_f32_16x16x32_bf16(av0, bv, acc2[0][dt], 0, 0, 0);
                acc2[1][dt] = __builtin_amdgcn_mfma_f32_16x16x32_bf16(av1, bv, acc2[1][dt], 0, 0, 0);
            }
        }
        __syncthreads();   // xsT reads done -> next tile may overwrite
    }

    // parts store via stg (aliases xsT)
    ushort* stg = sh.u.q.xsT;
    #pragma unroll
    for (int kt = 0; kt < 2; ++kt)
        #pragma unroll
        for (int dt = 0; dt < 8; ++dt)
            #pragma unroll
            for (int r = 0; r < 4; ++r)
                stg[(kt * 16 + g * 4 + r) * 520 + w * 128 + dt * 16 + lo] = f2b(acc2[kt][dt][r]);
    __syncthreads();
    #pragma unroll
    for (int j = 0; j < 8; ++j) {
        int k = w * 8 + j;
        s16x8 v = *(const s16x8*)&stg[k * 520 + l * 8];
        *(s16x8*)(parts + ((size_t)(s64 * 16 + b) * 32 + k) * 512 + l * 8) = v;
    }
}

// kC2: 512 blocks (b, k) x 256 thr: assign_sum, dist (k==0), entropy (bid 0),
// vlad = sum_s parts - CT*as, intra-D normalize, write out (B,K,D).
__global__ __launch_bounds__(256) void kC2(const float* __restrict__ ws,
    const ushort* __restrict__ parts, float* __restrict__ out)
{
    __shared__ float pm[256];
    __shared__ float asL[32];
    __shared__ float red[4];
    const int bid = blockIdx.x;
    const int b = bid >> 5, k = bid & 31;
    const int t = threadIdx.x;
    {
        int kk = t & 31, i = t >> 5;   // 0..7
        float a = 0.f;
        #pragma unroll
        for (int ii = 0; ii < 8; ++ii)
            a += ws[WS_ASP_F + (size_t)(b * 64 + ii * 8 + i) * 32 + kk];
        pm[t] = a;
    }
    __syncthreads();
    if (t < 32) {
        float a = 0.f;
        #pragma unroll
        for (int i = 0; i < 8; ++i) a += pm[i * 32 + t];
        asL[t] = a;
    }
    __syncthreads();
    if (k == 0 && t < 32) {
        float a = asL[t];
        float mx = a;
        #pragma unroll
        for (int m = 16; m; m >>= 1) mx = fmaxf(mx, __shfl_xor(mx, m));
        float e = __expf(a - mx), ssum = e;
        #pragma unroll
        for (int m = 16; m; m >>= 1) ssum += __shfl_xor(ssum, m);
        out[OFF_DIST + b * 32 + t] = a - mx - logf(ssum);
    }
    if (bid == 0 && (t >> 6) == 1) {
        int ll = t & 63;
        float es = 0.f, ms = 0.f;
        for (int i = ll; i < 1024; i += 64) {
            es += ws[WS_ENTP_F + i];
            ms += ws[WS_MSKP_F + i];
        }
        #pragma unroll
        for (int m = 32; m; m >>= 1) { es += __shfl_xor(es, m); ms += __shfl_xor(ms, m); }
        if (ll == 0) out[OFF_ENT] = es / ms;
    }
    const float as = asL[k];
    const int d0 = t * 2;
    float a0 = 0.f, a1 = 0.f;
    #pragma unroll
    for (int s = 0; s < 16; ++s) {
        unsigned v = *(const unsigned*)(parts + ((size_t)(s * 16 + b) * 32 + k) * 512 + d0);
        a0 += b2f((ushort)(v & 0xffffu));
        a1 += b2f((ushort)(v >> 16));
    }
    float2 ctv = *(const float2*)(ws + WS_CT_F + (size_t)k * 512 + d0);
    float v0 = a0 - ctv.x * as;
    float v1 = a1 - ctv.y * as;
    float sq = v0 * v0 + v1 * v1;
    #pragma unroll
    for (int m = 32; m; m >>= 1) sq += __shfl_xor(sq, m);
    if ((t & 63) == 0) red[t >> 6] = sq;
    __syncthreads();
    float sc = 1.f / fmaxf(sqrtf(red[0] + red[1] + red[2] + red[3]), EPSF);
    float2 o = make_float2(v0 * sc, v1 * sc);
    *(float2*)(out + (size_t)(b * 32 + k) * 512 + d0) = o;
}

extern "C" void kernel_launch(void* const* d_in, const int* in_sizes, int n_in,
                              void* d_out, int out_size, void* d_ws, size_t ws_size,
                              hipStream_t stream)
{
    const float* x    = (const float*)d_in[0];
    const float* mask = (const float*)d_in[1];
    const float* W    = (const float*)d_in[2];
    const float* bias = (const float*)d_in[3];
    const float* cent = (const float*)d_in[4];
    float* out = (float*)d_out;
    float* ws  = (float*)d_ws;
    ushort* parts = (ushort*)(ws + WS_PART_F);

    kA2<<<dim3(256), dim3(256), 0, stream>>>(x, mask, W, bias, cent, ws, parts);
    kC2<<<dim3(512), dim3(256), 0, stream>>>(ws, parts, out);
}